// Round 15
// baseline (992.917 us; speedup 1.0000x reference)
//
#include <hip/hip_runtime.h>
#include <math.h>

#define BB    4
#define CINN  32
#define COUTT 32
#define KCL   32
#define MM    16
#define AREA  9
#define SS    4096
#define FF    288
#define KMIT  10
#define NBPB  16     // blocks per batch
#define NB    (BB*NBPB)
#define TPB   256    // 1 thread = 1 point
#define PITER 50     // probe iterations

typedef float f32x4 __attribute__((ext_vector_type(4)));

// ---- coherent (cross-XCD) point ops: bypass L1+L2, served at coherent point ----
__device__ __forceinline__ void store_x4_coh(float* p, f32x4 v) {
    asm volatile("global_store_dwordx4 %0, %1, off sc0 sc1" :: "v"(p), "v"(v) : "memory");
}
__device__ __forceinline__ void store_dw_coh(float* p, float v) {
    asm volatile("global_store_dword %0, %1, off sc0 sc1" :: "v"(p), "v"(v) : "memory");
}
__device__ __forceinline__ void store_u32_coh(unsigned* p, unsigned v) {
    asm volatile("global_store_dword %0, %1, off sc0 sc1" :: "v"(p), "v"(v) : "memory");
}
__device__ __forceinline__ unsigned spin_ld_coh(const unsigned* p) {
    unsigned r;
    asm volatile("global_load_dword %0, %1, off sc0 sc1\n\ts_waitcnt vmcnt(0)"
                 : "=v"(r) : "v"(p) : "memory");
    return r;
}
__device__ __forceinline__ f32x4 load_x4_coh(const float* p) {
    f32x4 r;
    asm volatile("global_load_dwordx4 %0, %1, off sc0 sc1" : "=v"(r) : "v"(p) : "memory");
    return r;
}
__device__ __forceinline__ float load_dw_coh(const float* p) {
    float r;
    asm volatile("global_load_dword %0, %1, off sc0 sc1" : "=v"(r) : "v"(p) : "memory");
    return r;
}

// exact-order distance for rows k2 and k2+1: two independent chains, each accumulating
// in channel order c0..c31 — bit-identical to the single-chain r12 assign.
#define DIST2(RA, RB, KOFF)                                                     \
    {                                                                           \
        float dA = 0.f, dB = 0.f;                                               \
        _Pragma("unroll")                                                       \
        for (int q = 0; q < 8; ++q) {                                           \
            _Pragma("unroll")                                                   \
            for (int jj = 0; jj < 4; ++jj) {                                    \
                float a = p[q * 4 + jj] - RA[q][jj]; dA += a * a;               \
                float bb = p[q * 4 + jj] - RB[q][jj]; dB += bb * bb;            \
            }                                                                   \
        }                                                                       \
        if (dA < dmin) { dmin = dA; kmin = (KOFF); }                            \
        if (dB < dmin) { dmin = dB; kmin = (KOFF) + 1; }                        \
    }

// ---------------- fused: feat + init + 10x Lloyd + final assign + MLP heads ----------------
__global__ __launch_bounds__(TPB) void kmeans_mlp_fused(
        const float* __restrict__ x,
        int* __restrict__ idx, float* __restrict__ psums, float* __restrict__ pcnts,
        unsigned* __restrict__ barcnt, unsigned* __restrict__ barver,
        float* __restrict__ centG,
        const float* __restrict__ kh_w1, const float* __restrict__ kh_b1,
        const float* __restrict__ kh_w2, const float* __restrict__ kh_b2,
        const float* __restrict__ area_w, const float* __restrict__ area_b,
        const float* __restrict__ cin_w, const float* __restrict__ cin_b,
        const float* __restrict__ cout_w, const float* __restrict__ cout_b,
        const float* __restrict__ bh_w1, const float* __restrict__ bh_b1,
        const float* __restrict__ bh_w2, const float* __restrict__ bh_b2,
        const float* __restrict__ bh_w3, const float* __restrict__ bh_b3,
        float* __restrict__ wprod, float* __restrict__ wcoutA, float* __restrict__ biasA)
{
    __shared__ __align__(16) float cl[KCL * CINN];     // 4 KB centroids (block copy)
    __shared__ __align__(16) float pl[TPB * CINN];     // 32 KB point features
    __shared__ int   kms[TPB];                         // 1 KB assignments
    __shared__ float wsums[4][KCL * 33];               // 16.9 KB wave partials (padded)
    __shared__ float wcnt[4][KCL];
    __shared__ unsigned last_sh;
    __shared__ float f1s[4][MM], g1s[4][MM], f2s[4][MM], g2s[4][MM];
    __shared__ float wcs[4][CINN], was[4][AREA];

    int blk = blockIdx.x;
    int b   = blk >> 4;
    int nbq = blk & 15;
    int tid = threadIdx.x;
    int lane = tid & 63, wid = tid >> 6;
    int s = (nbq << 8) + tid;
    int h = s >> 6, w = s & 63;
    const float* xb = x + ((size_t)(b * CINN) << 12);
    const int offA[9] = { -65, -64, -63, -1, 0, 1, 63, 64, 65 };

    // ---- feat of own point (3x3 box mean) into registers ----
    float p[CINN];
    {
        const float* xc = xb + (h << 6) + w;
        bool vh0 = h > 0, vh2 = h < 63, vw0 = w > 0, vw2 = w < 63;
        bool va[9] = { vh0&&vw0, vh0, vh0&&vw2, vw0, true, vw2, vh2&&vw0, vh2, vh2&&vw2 };
        for (int c = 0; c < CINN; ++c) {
            const float* xp = xc + (c << 12);
            float sm = 0.f;
            #pragma unroll
            for (int a = 0; a < 9; ++a) sm += va[a] ? xp[offA[a]] : 0.f;
            p[c] = sm * (1.f / 9.f);
        }
    }
    // ---- write p to LDS once (rotated: conflict-free) ----
    #pragma unroll
    for (int j = 0; j < CINN; ++j) {
        int c = (tid + j) & 31;
        pl[tid * CINN + c] = p[c];
    }
    // ---- redundant init: every block computes the 32 linspace init centroids itself ----
    {
        int kinit = tid >> 3, cg = (tid & 7) << 2;
        int si = (kinit * 4095) / 31;
        int hi_ = si >> 6, wi_ = si & 63;
        bool vh0 = hi_ > 0, vh2 = hi_ < 63, vw0 = wi_ > 0, vw2 = wi_ < 63;
        bool va[9] = { vh0&&vw0, vh0, vh0&&vw2, vw0, true, vw2, vh2&&vw0, vh2, vh2&&vw2 };
        const float* xc = xb + (hi_ << 6) + wi_;
        #pragma unroll
        for (int j = 0; j < 4; ++j) {
            const float* xp = xc + ((size_t)(cg + j) << 12);
            float sm = 0.f;
            #pragma unroll
            for (int a = 0; a < 9; ++a) sm += va[a] ? xp[offA[a]] : 0.f;
            cl[kinit * CINN + cg + j] = sm * (1.f / 9.f);
        }
    }
    __syncthreads();

    int kq = tid >> 3, c4 = (tid & 7) << 2;          // this thread's (k, 4-channel) quad
    int kb = (lane >> 3) << 2, cw = (lane & 7) << 2; // reduction slot: 4 k's, one c-quad
    int cwq = cw >> 2;
    unsigned* cntb = barcnt + b * 16;                // one 64B line per batch
    unsigned* verb = barver + b * 16;
    float* cgb = centG + ((size_t)b << 10);
    const f32x4* cl4 = reinterpret_cast<const f32x4*>(cl);
    const f32x4* pl4 = reinterpret_cast<const f32x4*>(pl);

    for (int it = 0; it < KMIT; ++it) {
        // ---- assign: 2-k interleaved exact chains, rows preloaded to registers ----
        float dmin = 3.4e38f; int kmin = 0;
        #pragma unroll 2
        for (int k2 = 0; k2 < KCL; k2 += 2) {
            f32x4 ra[8], rb[8];
            #pragma unroll
            for (int q = 0; q < 8; ++q) { ra[q] = cl4[k2 * 8 + q]; rb[q] = cl4[k2 * 8 + 8 + q]; }
            DIST2(ra, rb, k2);
        }
        kms[tid] = kmin;
        __syncthreads();
        // ---- one-hot dense reduction: each wave sums its OWN 64 points (counts folded);
        //      unrolled x4 with batched loads; accumulation in strict point order ----
        {
            f32x4 a0 = 0.f, a1 = 0.f, a2 = 0.f, a3 = 0.f, an4 = 0.f;
            int sbase = wid << 6;
            for (int i = 0; i < 64; i += 4) {
                int km0 = kms[sbase + i + 0];
                int km1 = kms[sbase + i + 1];
                int km2 = kms[sbase + i + 2];
                int km3 = kms[sbase + i + 3];
                f32x4 pv0 = pl4[(sbase + i + 0) * 8 + cwq];
                f32x4 pv1 = pl4[(sbase + i + 1) * 8 + cwq];
                f32x4 pv2 = pl4[(sbase + i + 2) * 8 + cwq];
                f32x4 pv3 = pl4[(sbase + i + 3) * 8 + cwq];
                float m00 = (km0 == kb + 0) ? 1.f : 0.f;
                float m01 = (km0 == kb + 1) ? 1.f : 0.f;
                float m02 = (km0 == kb + 2) ? 1.f : 0.f;
                float m03 = (km0 == kb + 3) ? 1.f : 0.f;
                a0 += m00 * pv0; a1 += m01 * pv0; a2 += m02 * pv0; a3 += m03 * pv0;
                an4[0] += m00; an4[1] += m01; an4[2] += m02; an4[3] += m03;
                float m10 = (km1 == kb + 0) ? 1.f : 0.f;
                float m11 = (km1 == kb + 1) ? 1.f : 0.f;
                float m12 = (km1 == kb + 2) ? 1.f : 0.f;
                float m13 = (km1 == kb + 3) ? 1.f : 0.f;
                a0 += m10 * pv1; a1 += m11 * pv1; a2 += m12 * pv1; a3 += m13 * pv1;
                an4[0] += m10; an4[1] += m11; an4[2] += m12; an4[3] += m13;
                float m20 = (km2 == kb + 0) ? 1.f : 0.f;
                float m21 = (km2 == kb + 1) ? 1.f : 0.f;
                float m22 = (km2 == kb + 2) ? 1.f : 0.f;
                float m23 = (km2 == kb + 3) ? 1.f : 0.f;
                a0 += m20 * pv2; a1 += m21 * pv2; a2 += m22 * pv2; a3 += m23 * pv2;
                an4[0] += m20; an4[1] += m21; an4[2] += m22; an4[3] += m23;
                float m30 = (km3 == kb + 0) ? 1.f : 0.f;
                float m31 = (km3 == kb + 1) ? 1.f : 0.f;
                float m32 = (km3 == kb + 2) ? 1.f : 0.f;
                float m33 = (km3 == kb + 3) ? 1.f : 0.f;
                a0 += m30 * pv3; a1 += m31 * pv3; a2 += m32 * pv3; a3 += m33 * pv3;
                an4[0] += m30; an4[1] += m31; an4[2] += m32; an4[3] += m33;
            }
            #pragma unroll
            for (int cc = 0; cc < 4; ++cc) {
                wsums[wid][(kb + 0) * 33 + cw + cc] = a0[cc];
                wsums[wid][(kb + 1) * 33 + cw + cc] = a1[cc];
                wsums[wid][(kb + 2) * 33 + cw + cc] = a2[cc];
                wsums[wid][(kb + 3) * 33 + cw + cc] = a3[cc];
            }
            if (cw == 0) {
                wcnt[wid][kb + 0] = an4[0]; wcnt[wid][kb + 1] = an4[1];
                wcnt[wid][kb + 2] = an4[2]; wcnt[wid][kb + 3] = an4[3];
            }
        }
        __syncthreads();
        // ---- combine 4 wave partials, coherent write (parity double-buffered) ----
        int par = it & 1;
        float* ps = psums + ((size_t)(par * NB) << 10);
        float* pc = pcnts + par * NB * KCL;
        {
            f32x4 v = 0.f;
            #pragma unroll
            for (int ww = 0; ww < 4; ++ww) {
                v.x += wsums[ww][kq * 33 + c4 + 0];
                v.y += wsums[ww][kq * 33 + c4 + 1];
                v.z += wsums[ww][kq * 33 + c4 + 2];
                v.w += wsums[ww][kq * 33 + c4 + 3];
            }
            store_x4_coh(ps + ((size_t)blk << 10) + (kq << 5) + c4, v);
            if (tid < KCL)
                store_dw_coh(pc + blk * KCL + tid,
                             wcnt[0][tid] + wcnt[1][tid] + wcnt[2][tid] + wcnt[3][tid]);
        }
        asm volatile("s_waitcnt vmcnt(0)" ::: "memory");   // this wave's stores retired
        __syncthreads();                                   // => whole block's stores retired
        // ---- per-batch arrival; LAST block becomes the updater ----
        if (tid == 0) {
            unsigned old = atomicAdd(cntb, 1u);
            last_sh = (old == (unsigned)(NBPB * (it + 1)) - 1u) ? 1u : 0u;
        }
        __syncthreads();
        if (last_sh) {
            // ---- single-updater: fixed-order fp32 reduction (deterministic) ----
            f32x4 v[NBPB]; float cn[NBPB];
            #pragma unroll
            for (int q = 0; q < NBPB; ++q)
                v[q] = load_x4_coh(ps + ((size_t)((b << 4) + q) << 10) + (kq << 5) + c4);
            #pragma unroll
            for (int q = 0; q < NBPB; ++q)
                cn[q] = load_dw_coh(pc + ((b << 4) + q) * KCL + kq);
            asm volatile("s_waitcnt vmcnt(0)" ::: "memory");
            __builtin_amdgcn_sched_barrier(0);
            float sx = v[0][0], sy = v[0][1], sz = v[0][2], sw = v[0][3], ct = cn[0];
            #pragma unroll
            for (int q = 1; q < NBPB; ++q) {
                sx += v[q][0]; sy += v[q][1]; sz += v[q][2]; sw += v[q][3]; ct += cn[q];
            }
            float ctm = fmaxf(ct, 1.f);
            float4 old4 = *reinterpret_cast<const float4*>(&cl[kq * CINN + c4]);
            f32x4 nc;
            nc[0] = (ct > 0.f) ? sx / ctm : old4.x;
            nc[1] = (ct > 0.f) ? sy / ctm : old4.y;
            nc[2] = (ct > 0.f) ? sz / ctm : old4.z;
            nc[3] = (ct > 0.f) ? sw / ctm : old4.w;
            store_x4_coh(cgb + (kq << 5) + c4, nc);
            asm volatile("s_waitcnt vmcnt(0)" ::: "memory"); // centroids at coherent point
            __syncthreads();                                 // whole block's stores retired
            if (tid == 0) store_u32_coh(verb, (unsigned)(it + 1));  // publish
            cl[kq * CINN + c4 + 0] = nc[0];
            cl[kq * CINN + c4 + 1] = nc[1];
            cl[kq * CINN + c4 + 2] = nc[2];
            cl[kq * CINN + c4 + 3] = nc[3];
        } else {
            // ---- spinners: poll version line with backoff, then one 4KB coherent read ----
            if (tid == 0) {
                while (spin_ld_coh(verb) < (unsigned)(it + 1))
                    __builtin_amdgcn_s_sleep(8);
            }
            __syncthreads();
            f32x4 nc = load_x4_coh(cgb + (kq << 5) + c4);
            asm volatile("s_waitcnt vmcnt(0)" ::: "memory");
            __builtin_amdgcn_sched_barrier(0);
            cl[kq * CINN + c4 + 0] = nc[0];
            cl[kq * CINN + c4 + 1] = nc[1];
            cl[kq * CINN + c4 + 2] = nc[2];
            cl[kq * CINN + c4 + 3] = nc[3];
        }
        __syncthreads();
    }

    // ---- final assign with c_10 ----
    {
        float dmin = 3.4e38f; int kmin = 0;
        #pragma unroll 2
        for (int k2 = 0; k2 < KCL; k2 += 2) {
            f32x4 ra[8], rb[8];
            #pragma unroll
            for (int q = 0; q < 8; ++q) { ra[q] = cl4[k2 * 8 + q]; rb[q] = cl4[k2 * 8 + 8 + q]; }
            DIST2(ra, rb, k2);
        }
        idx[(size_t)b * SS + s] = kmin;
    }

    // ---- MLP heads on the nbq==0 block of each batch (has final centroids in cl) ----
    if (nbq == 0) {
        int k2 = tid >> 6;                     // 4 clusters in parallel, 64 lanes each
        for (int kk = 0; kk < 8; ++kk) {
            int k = kk * 4 + k2;
            const float* cc = &cl[k * CINN];
            if (lane < MM) {
                float a = kh_b1[lane], a2 = bh_b1[lane];
                for (int c = 0; c < CINN; ++c) {
                    float cv = cc[c];
                    a  += cv * kh_w1[c * MM + lane];
                    a2 += cv * bh_w1[c * MM + lane];
                }
                f1s[k2][lane] = fmaxf(a, 0.f); g1s[k2][lane] = fmaxf(a2, 0.f);
            }
            __syncthreads();
            if (lane < MM) {
                float a = kh_b2[lane], a2 = bh_b2[lane];
                for (int m = 0; m < MM; ++m) {
                    a  += f1s[k2][m] * kh_w2[m * MM + lane];
                    a2 += g1s[k2][m] * bh_w2[m * MM + lane];
                }
                f2s[k2][lane] = fmaxf(a, 0.f); g2s[k2][lane] = fmaxf(a2, 0.f);
            }
            __syncthreads();
            int bk = b * KCL + k;
            if (lane < CINN) {
                float ac = cin_b[lane], ao = cout_b[lane], ab = bh_b3[lane];
                for (int m = 0; m < MM; ++m) {
                    float f2v = f2s[k2][m];
                    ac += f2v * cin_w[m * CINN + lane];
                    ao += f2v * cout_w[m * COUTT + lane];
                    ab += g2s[k2][m] * bh_w3[m * COUTT + lane];
                }
                wcs[k2][lane] = 1.f / (1.f + expf(-ac));
                wcoutA[(size_t)bk * COUTT + lane] = 1.f / (1.f + expf(-ao));
                biasA[(size_t)bk * COUTT + lane] = ab;
            } else if (lane < CINN + AREA) {
                int a9 = lane - CINN;
                float aa = area_b[a9];
                for (int m = 0; m < MM; ++m) aa += f2s[k2][m] * area_w[m * AREA + a9];
                was[k2][a9] = 1.f / (1.f + expf(-aa));
            }
            __syncthreads();
            for (int f = lane; f < FF; f += 64)
                wprod[(size_t)bk * FF + f] = wcs[k2][f / 9] * was[k2][f % 9];
        }
    }
}

// ---------------- DIAGNOSTIC PROBE 1: assign-only, 50 iters, no sync ----------------
__global__ __launch_bounds__(TPB) void probe_assign(
        const float* __restrict__ x, float* __restrict__ sink)
{
    __shared__ __align__(16) float cl[KCL * CINN];
    __shared__ int kms[TPB];
    int blk = blockIdx.x;
    int b = blk >> 4, nbq = blk & 15, tid = threadIdx.x;
    int s = (nbq << 8) + tid;
    int h = s >> 6, w = s & 63;
    const float* xb = x + ((size_t)(b * CINN) << 12);
    const int offA[9] = { -65, -64, -63, -1, 0, 1, 63, 64, 65 };
    float p[CINN];
    {
        const float* xc = xb + (h << 6) + w;
        bool vh0 = h > 0, vh2 = h < 63, vw0 = w > 0, vw2 = w < 63;
        bool va[9] = { vh0&&vw0, vh0, vh0&&vw2, vw0, true, vw2, vh2&&vw0, vh2, vh2&&vw2 };
        for (int c = 0; c < CINN; ++c) {
            const float* xp = xc + (c << 12);
            float sm = 0.f;
            #pragma unroll
            for (int a = 0; a < 9; ++a) sm += va[a] ? xp[offA[a]] : 0.f;
            p[c] = sm * (1.f / 9.f);
        }
    }
    {
        int kinit = tid >> 3, cg = (tid & 7) << 2;
        int si = (kinit * 4095) / 31;
        int hi_ = si >> 6, wi_ = si & 63;
        bool vh0 = hi_ > 0, vh2 = hi_ < 63, vw0 = wi_ > 0, vw2 = wi_ < 63;
        bool va[9] = { vh0&&vw0, vh0, vh0&&vw2, vw0, true, vw2, vh2&&vw0, vh2, vh2&&vw2 };
        const float* xc = xb + (hi_ << 6) + wi_;
        #pragma unroll
        for (int j = 0; j < 4; ++j) {
            const float* xp = xc + ((size_t)(cg + j) << 12);
            float sm = 0.f;
            #pragma unroll
            for (int a = 0; a < 9; ++a) sm += va[a] ? xp[offA[a]] : 0.f;
            cl[kinit * CINN + cg + j] = sm * (1.f / 9.f);
        }
    }
    __syncthreads();
    const f32x4* cl4 = reinterpret_cast<const f32x4*>(cl);
    float accs = 0.f;
    for (int it = 0; it < PITER; ++it) {
        float dmin = 3.4e38f; int kmin = 0;
        #pragma unroll 2
        for (int k2 = 0; k2 < KCL; k2 += 2) {
            f32x4 ra[8], rb[8];
            #pragma unroll
            for (int q = 0; q < 8; ++q) { ra[q] = cl4[k2 * 8 + q]; rb[q] = cl4[k2 * 8 + 8 + q]; }
            DIST2(ra, rb, k2);
        }
        kms[tid] = kmin;
        accs += dmin + (float)kmin;
        __syncthreads();
        if (tid == 0) cl[it & 1023] += 1e-38f;   // defeat LICM; value unchanged
        accs += (float)kms[(tid + it) & 255];    // keep kms live
        __syncthreads();
    }
    sink[(size_t)blk * TPB + tid] = accs;
}

// ------- DIAGNOSTIC PROBE 2: assign+scan+wsums+combine, 50 iters, no sync/stores -------
__global__ __launch_bounds__(TPB) void probe_compute(
        const float* __restrict__ x, float* __restrict__ sink)
{
    __shared__ __align__(16) float cl[KCL * CINN];
    __shared__ __align__(16) float pl[TPB * CINN];
    __shared__ int kms[TPB];
    __shared__ float wsums[4][KCL * 33];
    __shared__ float wcnt[4][KCL];
    int blk = blockIdx.x;
    int b = blk >> 4, nbq = blk & 15, tid = threadIdx.x;
    int lane = tid & 63, wid = tid >> 6;
    int s = (nbq << 8) + tid;
    int h = s >> 6, w = s & 63;
    const float* xb = x + ((size_t)(b * CINN) << 12);
    const int offA[9] = { -65, -64, -63, -1, 0, 1, 63, 64, 65 };
    float p[CINN];
    {
        const float* xc = xb + (h << 6) + w;
        bool vh0 = h > 0, vh2 = h < 63, vw0 = w > 0, vw2 = w < 63;
        bool va[9] = { vh0&&vw0, vh0, vh0&&vw2, vw0, true, vw2, vh2&&vw0, vh2, vh2&&vw2 };
        for (int c = 0; c < CINN; ++c) {
            const float* xp = xc + (c << 12);
            float sm = 0.f;
            #pragma unroll
            for (int a = 0; a < 9; ++a) sm += va[a] ? xp[offA[a]] : 0.f;
            p[c] = sm * (1.f / 9.f);
        }
    }
    #pragma unroll
    for (int j = 0; j < CINN; ++j) {
        int c = (tid + j) & 31;
        pl[tid * CINN + c] = p[c];
    }
    {
        int kinit = tid >> 3, cg = (tid & 7) << 2;
        int si = (kinit * 4095) / 31;
        int hi_ = si >> 6, wi_ = si & 63;
        bool vh0 = hi_ > 0, vh2 = hi_ < 63, vw0 = wi_ > 0, vw2 = wi_ < 63;
        bool va[9] = { vh0&&vw0, vh0, vh0&&vw2, vw0, true, vw2, vh2&&vw0, vh2, vh2&&vw2 };
        const float* xc = xb + (hi_ << 6) + wi_;
        #pragma unroll
        for (int j = 0; j < 4; ++j) {
            const float* xp = xc + ((size_t)(cg + j) << 12);
            float sm = 0.f;
            #pragma unroll
            for (int a = 0; a < 9; ++a) sm += va[a] ? xp[offA[a]] : 0.f;
            cl[kinit * CINN + cg + j] = sm * (1.f / 9.f);
        }
    }
    __syncthreads();
    int kq = tid >> 3, c4 = (tid & 7) << 2;
    int kb = (lane >> 3) << 2, cw = (lane & 7) << 2;
    int cwq = cw >> 2;
    const f32x4* cl4 = reinterpret_cast<const f32x4*>(cl);
    const f32x4* pl4 = reinterpret_cast<const f32x4*>(pl);
    f32x4 accv = {0.f, 0.f, 0.f, 0.f};
    float accs = 0.f;
    for (int it = 0; it < PITER; ++it) {
        float dmin = 3.4e38f; int kmin = 0;
        #pragma unroll 2
        for (int k2 = 0; k2 < KCL; k2 += 2) {
            f32x4 ra[8], rb[8];
            #pragma unroll
            for (int q = 0; q < 8; ++q) { ra[q] = cl4[k2 * 8 + q]; rb[q] = cl4[k2 * 8 + 8 + q]; }
            DIST2(ra, rb, k2);
        }
        kms[tid] = kmin;
        accs += dmin;
        __syncthreads();
        {
            f32x4 a0 = 0.f, a1 = 0.f, a2 = 0.f, a3 = 0.f, an4 = 0.f;
            int sbase = wid << 6;
            for (int i = 0; i < 64; i += 4) {
                int km0 = kms[sbase + i + 0];
                int km1 = kms[sbase + i + 1];
                int km2 = kms[sbase + i + 2];
                int km3 = kms[sbase + i + 3];
                f32x4 pv0 = pl4[(sbase + i + 0) * 8 + cwq];
                f32x4 pv1 = pl4[(sbase + i + 1) * 8 + cwq];
                f32x4 pv2 = pl4[(sbase + i + 2) * 8 + cwq];
                f32x4 pv3 = pl4[(sbase + i + 3) * 8 + cwq];
                float m00 = (km0 == kb + 0) ? 1.f : 0.f;
                float m01 = (km0 == kb + 1) ? 1.f : 0.f;
                float m02 = (km0 == kb + 2) ? 1.f : 0.f;
                float m03 = (km0 == kb + 3) ? 1.f : 0.f;
                a0 += m00 * pv0; a1 += m01 * pv0; a2 += m02 * pv0; a3 += m03 * pv0;
                an4[0] += m00; an4[1] += m01; an4[2] += m02; an4[3] += m03;
                float m10 = (km1 == kb + 0) ? 1.f : 0.f;
                float m11 = (km1 == kb + 1) ? 1.f : 0.f;
                float m12 = (km1 == kb + 2) ? 1.f : 0.f;
                float m13 = (km1 == kb + 3) ? 1.f : 0.f;
                a0 += m10 * pv1; a1 += m11 * pv1; a2 += m12 * pv1; a3 += m13 * pv1;
                an4[0] += m10; an4[1] += m11; an4[2] += m12; an4[3] += m13;
                float m20 = (km2 == kb + 0) ? 1.f : 0.f;
                float m21 = (km2 == kb + 1) ? 1.f : 0.f;
                float m22 = (km2 == kb + 2) ? 1.f : 0.f;
                float m23 = (km2 == kb + 3) ? 1.f : 0.f;
                a0 += m20 * pv2; a1 += m21 * pv2; a2 += m22 * pv2; a3 += m23 * pv2;
                an4[0] += m20; an4[1] += m21; an4[2] += m22; an4[3] += m23;
                float m30 = (km3 == kb + 0) ? 1.f : 0.f;
                float m31 = (km3 == kb + 1) ? 1.f : 0.f;
                float m32 = (km3 == kb + 2) ? 1.f : 0.f;
                float m33 = (km3 == kb + 3) ? 1.f : 0.f;
                a0 += m30 * pv3; a1 += m31 * pv3; a2 += m32 * pv3; a3 += m33 * pv3;
                an4[0] += m30; an4[1] += m31; an4[2] += m32; an4[3] += m33;
            }
            #pragma unroll
            for (int cc = 0; cc < 4; ++cc) {
                wsums[wid][(kb + 0) * 33 + cw + cc] = a0[cc];
                wsums[wid][(kb + 1) * 33 + cw + cc] = a1[cc];
                wsums[wid][(kb + 2) * 33 + cw + cc] = a2[cc];
                wsums[wid][(kb + 3) * 33 + cw + cc] = a3[cc];
            }
            if (cw == 0) {
                wcnt[wid][kb + 0] = an4[0]; wcnt[wid][kb + 1] = an4[1];
                wcnt[wid][kb + 2] = an4[2]; wcnt[wid][kb + 3] = an4[3];
            }
        }
        __syncthreads();
        {
            f32x4 v = 0.f;
            #pragma unroll
            for (int ww = 0; ww < 4; ++ww) {
                v.x += wsums[ww][kq * 33 + c4 + 0];
                v.y += wsums[ww][kq * 33 + c4 + 1];
                v.z += wsums[ww][kq * 33 + c4 + 2];
                v.w += wsums[ww][kq * 33 + c4 + 3];
            }
            accv += v;
            if (tid < KCL) accs += wcnt[0][tid] + wcnt[1][tid] + wcnt[2][tid] + wcnt[3][tid];
        }
        if (tid == 0) cl[it & 1023] += 1e-38f;   // defeat LICM
        __syncthreads();
    }
    sink[(size_t)blk * TPB + tid] = accv[0] + accv[1] + accv[2] + accv[3] + accs;
}

// ---------------- main factorized conv ----------------
__global__ __launch_bounds__(256) void conv_kernel(
        const float* __restrict__ x, const int* __restrict__ idx,
        const float* __restrict__ wprod, const float* __restrict__ wcoutA,
        const float* __restrict__ biasA, const float* __restrict__ base,
        float* __restrict__ out) {
    __shared__ __align__(16) float bl[FF * COUTT];     // 36.9 KB
    int blk = blockIdx.x;                  // B*128
    int b = blk >> 7;
    int s0 = (blk & 127) << 5;             // 32 points per block
    int tid = threadIdx.x;
    for (int i = tid; i < FF * COUTT; i += 256) bl[i] = base[i];
    __syncthreads();
    int co4 = (tid & 7) << 2;              // 4 consecutive cout per thread
    int s = s0 + (tid >> 3);
    int h = s >> 6, w = s & 63;
    int k = idx[(size_t)b * SS + s];
    const float* wp = wprod + ((size_t)b * KCL + k) * FF;
    const float* xb = x + ((size_t)(b * CINN) << 12) + (h << 6) + w;
    bool vh0 = h > 0, vh2 = h < 63, vw0 = w > 0, vw2 = w < 63;
    bool va[9] = { vh0 && vw0, vh0, vh0 && vw2,
                   vw0,        true, vw2,
                   vh2 && vw0, vh2, vh2 && vw2 };
    const int offA[9] = { -65, -64, -63, -1, 0, 1, 63, 64, 65 };
    float ax = 0.f, ay = 0.f, az = 0.f, aw = 0.f;
    int f = 0;
    for (int c = 0; c < CINN; ++c) {
        const float* xp = xb + (c << 12);
        #pragma unroll
        for (int a = 0; a < 9; ++a) {
            float val = va[a] ? xp[offA[a]] : 0.f;
            float q = val * wp[f];
            float4 bb = *reinterpret_cast<const float4*>(&bl[(f << 5) + co4]);
            ax += q * bb.x; ay += q * bb.y; az += q * bb.z; aw += q * bb.w;
            ++f;
        }
    }
    const float* wo = wcoutA + ((size_t)b * KCL + k) * COUTT + co4;
    const float* bo = biasA + ((size_t)b * KCL + k) * COUTT + co4;
    float* op = out + ((size_t)(b * COUTT + co4) << 12) + s;
    op[0]     = wo[0] * ax + bo[0];
    op[4096]  = wo[1] * ay + bo[1];
    op[8192]  = wo[2] * az + bo[2];
    op[12288] = wo[3] * aw + bo[3];
}

extern "C" void kernel_launch(void* const* d_in, const int* in_sizes, int n_in,
                              void* d_out, int out_size, void* d_ws, size_t ws_size,
                              hipStream_t stream) {
    (void)in_sizes; (void)n_in; (void)out_size; (void)ws_size;
    const float* x      = (const float*)d_in[0];
    const float* kh_w1  = (const float*)d_in[1];
    const float* kh_b1  = (const float*)d_in[2];
    const float* kh_w2  = (const float*)d_in[3];
    const float* kh_b2  = (const float*)d_in[4];
    const float* area_w = (const float*)d_in[5];
    const float* area_b = (const float*)d_in[6];
    const float* cin_w  = (const float*)d_in[7];
    const float* cin_b  = (const float*)d_in[8];
    const float* cout_w = (const float*)d_in[9];
    const float* cout_b = (const float*)d_in[10];
    const float* base   = (const float*)d_in[11];
    const float* bh_w1  = (const float*)d_in[12];
    const float* bh_b1  = (const float*)d_in[13];
    const float* bh_w2  = (const float*)d_in[14];
    const float* bh_b2  = (const float*)d_in[15];
    const float* bh_w3  = (const float*)d_in[16];
    const float* bh_b3  = (const float*)d_in[17];
    float* out = (float*)d_out;

    unsigned* barcnt = (unsigned*)d_ws;                    // BB lines of 64B
    unsigned* barver = barcnt + 16 * BB;                   // BB lines of 64B
    float* centG = (float*)(barver + 16 * BB);             // BB*1024
    float* psums = centG + BB * 1024;                      // 2*NB*1024 = 131072
    float* pcnts = psums + (size_t)2 * NB * 1024;          // 2*NB*32   = 4096
    int*   idx   = (int*)(pcnts + 2 * NB * KCL);           // B*S
    float* wprod = (float*)(idx + BB * SS);                // B*K*F
    float* wco   = wprod + (size_t)BB * KCL * FF;          // B*K*COUT
    float* bia   = wco + BB * KCL * COUTT;                 // B*K*COUT
    float* sinkA = bia + BB * KCL * COUTT;                 // NB*TPB
    float* sinkC = sinkA + (size_t)NB * TPB;               // NB*TPB

    (void)hipMemsetAsync(barcnt, 0, 2 * 16 * BB * sizeof(unsigned), stream);
    kmeans_mlp_fused<<<NB, TPB, 0, stream>>>(x, idx, psums, pcnts, barcnt, barver, centG,
                                             kh_w1, kh_b1, kh_w2, kh_b2,
                                             area_w, area_b, cin_w, cin_b, cout_w, cout_b,
                                             bh_w1, bh_b1, bh_w2, bh_b2, bh_w3, bh_b3,
                                             wprod, wco, bia);
    conv_kernel<<<BB * 128, 256, 0, stream>>>(x, idx, wprod, wco, bia, base, out);
    probe_assign<<<NB, TPB, 0, stream>>>(x, sinkA);
    probe_compute<<<NB, TPB, 0, stream>>>(x, sinkC);
}

// Round 17
// 203.082 us; speedup vs baseline: 4.8892x; 4.8892x over previous
//
#include <hip/hip_runtime.h>
#include <math.h>

#define BB    4
#define CINN  32
#define COUTT 32
#define KCL   32
#define MM    16
#define AREA  9
#define SS    4096
#define FF    288
#define KMIT  10
#define NBPB  16     // blocks per batch
#define NB    (BB*NBPB)
#define TPB   256    // 1 thread = 1 point

typedef float f32x4 __attribute__((ext_vector_type(4)));

// ---- coherent (cross-XCD) point ops: bypass L1+L2, served at coherent point ----
__device__ __forceinline__ void store_x4_coh(float* p, f32x4 v) {
    asm volatile("global_store_dwordx4 %0, %1, off sc0 sc1" :: "v"(p), "v"(v) : "memory");
}
__device__ __forceinline__ void store_dw_coh(float* p, float v) {
    asm volatile("global_store_dword %0, %1, off sc0 sc1" :: "v"(p), "v"(v) : "memory");
}
__device__ __forceinline__ void store_u32_coh(unsigned* p, unsigned v) {
    asm volatile("global_store_dword %0, %1, off sc0 sc1" :: "v"(p), "v"(v) : "memory");
}
__device__ __forceinline__ unsigned spin_ld_coh(const unsigned* p) {
    unsigned r;
    asm volatile("global_load_dword %0, %1, off sc0 sc1\n\ts_waitcnt vmcnt(0)"
                 : "=v"(r) : "v"(p) : "memory");
    return r;
}
__device__ __forceinline__ f32x4 load_x4_coh(const float* p) {
    f32x4 r;
    asm volatile("global_load_dwordx4 %0, %1, off sc0 sc1" : "=v"(r) : "v"(p) : "memory");
    return r;
}
__device__ __forceinline__ float load_dw_coh(const float* p) {
    float r;
    asm volatile("global_load_dword %0, %1, off sc0 sc1" : "=v"(r) : "v"(p) : "memory");
    return r;
}

// exact-order distance for rows k2 and k2+1: two independent chains, each accumulating
// in channel order c0..c31 — FROZEN numeric path (r12/r14-verified against reference).
#define DIST2(RA, RB, KOFF)                                                     \
    {                                                                           \
        float dA = 0.f, dB = 0.f;                                               \
        _Pragma("unroll")                                                       \
        for (int q = 0; q < 8; ++q) {                                           \
            _Pragma("unroll")                                                   \
            for (int jj = 0; jj < 4; ++jj) {                                    \
                float a = p[q * 4 + jj] - RA[q][jj]; dA += a * a;               \
                float bb = p[q * 4 + jj] - RB[q][jj]; dB += bb * bb;            \
            }                                                                   \
        }                                                                       \
        if (dA < dmin) { dmin = dA; kmin = (KOFF); }                            \
        if (dB < dmin) { dmin = dB; kmin = (KOFF) + 1; }                        \
    }

// ---------------- fused: feat + init + 10x Lloyd + final assign + MLP heads ----------------
__global__ __launch_bounds__(TPB) void kmeans_mlp_fused(
        const float* __restrict__ x,
        int* __restrict__ idx, float* __restrict__ psums, float* __restrict__ pcnts,
        unsigned* __restrict__ barcnt, unsigned* __restrict__ barver,
        float* __restrict__ centG,
        const float* __restrict__ kh_w1, const float* __restrict__ kh_b1,
        const float* __restrict__ kh_w2, const float* __restrict__ kh_b2,
        const float* __restrict__ area_w, const float* __restrict__ area_b,
        const float* __restrict__ cin_w, const float* __restrict__ cin_b,
        const float* __restrict__ cout_w, const float* __restrict__ cout_b,
        const float* __restrict__ bh_w1, const float* __restrict__ bh_b1,
        const float* __restrict__ bh_w2, const float* __restrict__ bh_b2,
        const float* __restrict__ bh_w3, const float* __restrict__ bh_b3,
        float* __restrict__ wprod, float* __restrict__ wcoutA, float* __restrict__ biasA)
{
    __shared__ __align__(16) float cl[KCL * CINN];     // 4 KB centroids (block copy)
    __shared__ __align__(16) float pl[TPB * CINN];     // 32 KB point features
    __shared__ int   kms[TPB];                         // 1 KB assignments
    __shared__ float wsums[4][KCL * 33];               // 16.9 KB wave partials (padded)
    __shared__ float wcnt[4][KCL];
    __shared__ unsigned last_sh;
    __shared__ float f1s[4][MM], g1s[4][MM], f2s[4][MM], g2s[4][MM];
    __shared__ float wcs[4][CINN], was[4][AREA];

    int blk = blockIdx.x;
    int b   = blk >> 4;
    int nbq = blk & 15;
    int tid = threadIdx.x;
    int lane = tid & 63, wid = tid >> 6;
    int s = (nbq << 8) + tid;
    int h = s >> 6, w = s & 63;
    const float* xb = x + ((size_t)(b * CINN) << 12);
    const int offA[9] = { -65, -64, -63, -1, 0, 1, 63, 64, 65 };

    // ---- feat of own point (3x3 box mean) into registers ----
    float p[CINN];
    {
        const float* xc = xb + (h << 6) + w;
        bool vh0 = h > 0, vh2 = h < 63, vw0 = w > 0, vw2 = w < 63;
        bool va[9] = { vh0&&vw0, vh0, vh0&&vw2, vw0, true, vw2, vh2&&vw0, vh2, vh2&&vw2 };
        for (int c = 0; c < CINN; ++c) {
            const float* xp = xc + (c << 12);
            float sm = 0.f;
            #pragma unroll
            for (int a = 0; a < 9; ++a) sm += va[a] ? xp[offA[a]] : 0.f;
            p[c] = sm * (1.f / 9.f);
        }
    }
    // ---- write p to LDS once (rotated: conflict-free) ----
    #pragma unroll
    for (int j = 0; j < CINN; ++j) {
        int c = (tid + j) & 31;
        pl[tid * CINN + c] = p[c];
    }
    // ---- redundant init: every block computes the 32 linspace init centroids itself ----
    {
        int kinit = tid >> 3, cg = (tid & 7) << 2;
        int si = (kinit * 4095) / 31;
        int hi_ = si >> 6, wi_ = si & 63;
        bool vh0 = hi_ > 0, vh2 = hi_ < 63, vw0 = wi_ > 0, vw2 = wi_ < 63;
        bool va[9] = { vh0&&vw0, vh0, vh0&&vw2, vw0, true, vw2, vh2&&vw0, vh2, vh2&&vw2 };
        const float* xc = xb + (hi_ << 6) + wi_;
        #pragma unroll
        for (int j = 0; j < 4; ++j) {
            const float* xp = xc + ((size_t)(cg + j) << 12);
            float sm = 0.f;
            #pragma unroll
            for (int a = 0; a < 9; ++a) sm += va[a] ? xp[offA[a]] : 0.f;
            cl[kinit * CINN + cg + j] = sm * (1.f / 9.f);
        }
    }
    __syncthreads();

    int kq = tid >> 3, c4 = (tid & 7) << 2;          // this thread's (k, 4-channel) quad
    int kb = (lane >> 3) << 2, cw = (lane & 7) << 2; // reduction slot: 4 k's, one c-quad
    int cwq = cw >> 2;
    unsigned* cntb = barcnt + b * 16;                // one 64B line per batch
    unsigned* verb = barver + b * 16;
    float* cgb = centG + ((size_t)b << 10);
    const f32x4* cl4 = reinterpret_cast<const f32x4*>(cl);
    const f32x4* pl4 = reinterpret_cast<const f32x4*>(pl);

    for (int it = 0; it < KMIT; ++it) {
        // ---- assign: 2-k interleaved exact chains, rows preloaded to registers ----
        float dmin = 3.4e38f; int kmin = 0;
        #pragma unroll 2
        for (int k2 = 0; k2 < KCL; k2 += 2) {
            f32x4 ra[8], rb[8];
            #pragma unroll
            for (int q = 0; q < 8; ++q) { ra[q] = cl4[k2 * 8 + q]; rb[q] = cl4[k2 * 8 + 8 + q]; }
            DIST2(ra, rb, k2);
        }
        kms[tid] = kmin;
        __syncthreads();
        // ---- one-hot dense reduction: each wave sums its OWN 64 points (counts folded);
        //      unrolled x4 with batched loads; accumulation in strict point order ----
        {
            f32x4 a0 = 0.f, a1 = 0.f, a2 = 0.f, a3 = 0.f, an4 = 0.f;
            int sbase = wid << 6;
            for (int i = 0; i < 64; i += 4) {
                int km0 = kms[sbase + i + 0];
                int km1 = kms[sbase + i + 1];
                int km2 = kms[sbase + i + 2];
                int km3 = kms[sbase + i + 3];
                f32x4 pv0 = pl4[(sbase + i + 0) * 8 + cwq];
                f32x4 pv1 = pl4[(sbase + i + 1) * 8 + cwq];
                f32x4 pv2 = pl4[(sbase + i + 2) * 8 + cwq];
                f32x4 pv3 = pl4[(sbase + i + 3) * 8 + cwq];
                float m00 = (km0 == kb + 0) ? 1.f : 0.f;
                float m01 = (km0 == kb + 1) ? 1.f : 0.f;
                float m02 = (km0 == kb + 2) ? 1.f : 0.f;
                float m03 = (km0 == kb + 3) ? 1.f : 0.f;
                a0 += m00 * pv0; a1 += m01 * pv0; a2 += m02 * pv0; a3 += m03 * pv0;
                an4[0] += m00; an4[1] += m01; an4[2] += m02; an4[3] += m03;
                float m10 = (km1 == kb + 0) ? 1.f : 0.f;
                float m11 = (km1 == kb + 1) ? 1.f : 0.f;
                float m12 = (km1 == kb + 2) ? 1.f : 0.f;
                float m13 = (km1 == kb + 3) ? 1.f : 0.f;
                a0 += m10 * pv1; a1 += m11 * pv1; a2 += m12 * pv1; a3 += m13 * pv1;
                an4[0] += m10; an4[1] += m11; an4[2] += m12; an4[3] += m13;
                float m20 = (km2 == kb + 0) ? 1.f : 0.f;
                float m21 = (km2 == kb + 1) ? 1.f : 0.f;
                float m22 = (km2 == kb + 2) ? 1.f : 0.f;
                float m23 = (km2 == kb + 3) ? 1.f : 0.f;
                a0 += m20 * pv2; a1 += m21 * pv2; a2 += m22 * pv2; a3 += m23 * pv2;
                an4[0] += m20; an4[1] += m21; an4[2] += m22; an4[3] += m23;
                float m30 = (km3 == kb + 0) ? 1.f : 0.f;
                float m31 = (km3 == kb + 1) ? 1.f : 0.f;
                float m32 = (km3 == kb + 2) ? 1.f : 0.f;
                float m33 = (km3 == kb + 3) ? 1.f : 0.f;
                a0 += m30 * pv3; a1 += m31 * pv3; a2 += m32 * pv3; a3 += m33 * pv3;
                an4[0] += m30; an4[1] += m31; an4[2] += m32; an4[3] += m33;
            }
            #pragma unroll
            for (int cc = 0; cc < 4; ++cc) {
                wsums[wid][(kb + 0) * 33 + cw + cc] = a0[cc];
                wsums[wid][(kb + 1) * 33 + cw + cc] = a1[cc];
                wsums[wid][(kb + 2) * 33 + cw + cc] = a2[cc];
                wsums[wid][(kb + 3) * 33 + cw + cc] = a3[cc];
            }
            if (cw == 0) {
                wcnt[wid][kb + 0] = an4[0]; wcnt[wid][kb + 1] = an4[1];
                wcnt[wid][kb + 2] = an4[2]; wcnt[wid][kb + 3] = an4[3];
            }
        }
        __syncthreads();
        // ---- combine 4 wave partials, coherent write (parity double-buffered) ----
        int par = it & 1;
        float* ps = psums + ((size_t)(par * NB) << 10);
        float* pc = pcnts + par * NB * KCL;
        {
            f32x4 v = 0.f;
            #pragma unroll
            for (int ww = 0; ww < 4; ++ww) {
                v.x += wsums[ww][kq * 33 + c4 + 0];
                v.y += wsums[ww][kq * 33 + c4 + 1];
                v.z += wsums[ww][kq * 33 + c4 + 2];
                v.w += wsums[ww][kq * 33 + c4 + 3];
            }
            store_x4_coh(ps + ((size_t)blk << 10) + (kq << 5) + c4, v);
            if (tid < KCL)
                store_dw_coh(pc + blk * KCL + tid,
                             wcnt[0][tid] + wcnt[1][tid] + wcnt[2][tid] + wcnt[3][tid]);
        }
        asm volatile("s_waitcnt vmcnt(0)" ::: "memory");   // this wave's stores retired
        __syncthreads();                                   // => whole block's stores retired
        // ---- per-batch arrival; LAST block becomes the updater ----
        if (tid == 0) {
            unsigned old = atomicAdd(cntb, 1u);
            last_sh = (old == (unsigned)(NBPB * (it + 1)) - 1u) ? 1u : 0u;
        }
        __syncthreads();
        if (last_sh) {
            // ---- single-updater: fixed-order fp32 reduction (deterministic) ----
            f32x4 v[NBPB]; float cn[NBPB];
            #pragma unroll
            for (int q = 0; q < NBPB; ++q)
                v[q] = load_x4_coh(ps + ((size_t)((b << 4) + q) << 10) + (kq << 5) + c4);
            #pragma unroll
            for (int q = 0; q < NBPB; ++q)
                cn[q] = load_dw_coh(pc + ((b << 4) + q) * KCL + kq);
            asm volatile("s_waitcnt vmcnt(0)" ::: "memory");
            __builtin_amdgcn_sched_barrier(0);
            float sx = v[0][0], sy = v[0][1], sz = v[0][2], sw = v[0][3], ct = cn[0];
            #pragma unroll
            for (int q = 1; q < NBPB; ++q) {
                sx += v[q][0]; sy += v[q][1]; sz += v[q][2]; sw += v[q][3]; ct += cn[q];
            }
            float ctm = fmaxf(ct, 1.f);
            float4 old4 = *reinterpret_cast<const float4*>(&cl[kq * CINN + c4]);
            f32x4 nc;
            nc[0] = (ct > 0.f) ? sx / ctm : old4.x;
            nc[1] = (ct > 0.f) ? sy / ctm : old4.y;
            nc[2] = (ct > 0.f) ? sz / ctm : old4.z;
            nc[3] = (ct > 0.f) ? sw / ctm : old4.w;
            store_x4_coh(cgb + (kq << 5) + c4, nc);
            asm volatile("s_waitcnt vmcnt(0)" ::: "memory"); // centroids at coherent point
            __syncthreads();                                 // whole block's stores retired
            if (tid == 0) store_u32_coh(verb, (unsigned)(it + 1));  // publish
            cl[kq * CINN + c4 + 0] = nc[0];
            cl[kq * CINN + c4 + 1] = nc[1];
            cl[kq * CINN + c4 + 2] = nc[2];
            cl[kq * CINN + c4 + 3] = nc[3];
        } else {
            // ---- spinners: poll version line (fine-grained backoff), then 4KB coherent read ----
            if (tid == 0) {
                while (spin_ld_coh(verb) < (unsigned)(it + 1))
                    __builtin_amdgcn_s_sleep(2);
            }
            __syncthreads();
            f32x4 nc = load_x4_coh(cgb + (kq << 5) + c4);
            asm volatile("s_waitcnt vmcnt(0)" ::: "memory");
            __builtin_amdgcn_sched_barrier(0);
            cl[kq * CINN + c4 + 0] = nc[0];
            cl[kq * CINN + c4 + 1] = nc[1];
            cl[kq * CINN + c4 + 2] = nc[2];
            cl[kq * CINN + c4 + 3] = nc[3];
        }
        __syncthreads();
    }

    // ---- final assign with c_10 ----
    {
        float dmin = 3.4e38f; int kmin = 0;
        #pragma unroll 2
        for (int k2 = 0; k2 < KCL; k2 += 2) {
            f32x4 ra[8], rb[8];
            #pragma unroll
            for (int q = 0; q < 8; ++q) { ra[q] = cl4[k2 * 8 + q]; rb[q] = cl4[k2 * 8 + 8 + q]; }
            DIST2(ra, rb, k2);
        }
        idx[(size_t)b * SS + s] = kmin;
    }

    // ---- MLP heads on the nbq==0 block of each batch (has final centroids in cl) ----
    if (nbq == 0) {
        int k2 = tid >> 6;                     // 4 clusters in parallel, 64 lanes each
        for (int kk = 0; kk < 8; ++kk) {
            int k = kk * 4 + k2;
            const float* cc = &cl[k * CINN];
            if (lane < MM) {
                float a = kh_b1[lane], a2 = bh_b1[lane];
                for (int c = 0; c < CINN; ++c) {
                    float cv = cc[c];
                    a  += cv * kh_w1[c * MM + lane];
                    a2 += cv * bh_w1[c * MM + lane];
                }
                f1s[k2][lane] = fmaxf(a, 0.f); g1s[k2][lane] = fmaxf(a2, 0.f);
            }
            __syncthreads();
            if (lane < MM) {
                float a = kh_b2[lane], a2 = bh_b2[lane];
                for (int m = 0; m < MM; ++m) {
                    a  += f1s[k2][m] * kh_w2[m * MM + lane];
                    a2 += g1s[k2][m] * bh_w2[m * MM + lane];
                }
                f2s[k2][lane] = fmaxf(a, 0.f); g2s[k2][lane] = fmaxf(a2, 0.f);
            }
            __syncthreads();
            int bk = b * KCL + k;
            if (lane < CINN) {
                float ac = cin_b[lane], ao = cout_b[lane], ab = bh_b3[lane];
                for (int m = 0; m < MM; ++m) {
                    float f2v = f2s[k2][m];
                    ac += f2v * cin_w[m * CINN + lane];
                    ao += f2v * cout_w[m * COUTT + lane];
                    ab += g2s[k2][m] * bh_w3[m * COUTT + lane];
                }
                wcs[k2][lane] = 1.f / (1.f + expf(-ac));
                wcoutA[(size_t)bk * COUTT + lane] = 1.f / (1.f + expf(-ao));
                biasA[(size_t)bk * COUTT + lane] = ab;
            } else if (lane < CINN + AREA) {
                int a9 = lane - CINN;
                float aa = area_b[a9];
                for (int m = 0; m < MM; ++m) aa += f2s[k2][m] * area_w[m * AREA + a9];
                was[k2][a9] = 1.f / (1.f + expf(-aa));
            }
            __syncthreads();
            for (int f = lane; f < FF; f += 64)
                wprod[(size_t)bk * FF + f] = wcs[k2][f / 9] * was[k2][f % 9];
        }
    }
}

// ---------------- main factorized conv ----------------
__global__ __launch_bounds__(256) void conv_kernel(
        const float* __restrict__ x, const int* __restrict__ idx,
        const float* __restrict__ wprod, const float* __restrict__ wcoutA,
        const float* __restrict__ biasA, const float* __restrict__ base,
        float* __restrict__ out) {
    __shared__ __align__(16) float bl[FF * COUTT];     // 36.9 KB
    int blk = blockIdx.x;                  // B*128
    int b = blk >> 7;
    int s0 = (blk & 127) << 5;             // 32 points per block
    int tid = threadIdx.x;
    for (int i = tid; i < FF * COUTT; i += 256) bl[i] = base[i];
    __syncthreads();
    int co4 = (tid & 7) << 2;              // 4 consecutive cout per thread
    int s = s0 + (tid >> 3);
    int h = s >> 6, w = s & 63;
    int k = idx[(size_t)b * SS + s];
    const float* wp = wprod + ((size_t)b * KCL + k) * FF;
    const float* xb = x + ((size_t)(b * CINN) << 12) + (h << 6) + w;
    bool vh0 = h > 0, vh2 = h < 63, vw0 = w > 0, vw2 = w < 63;
    bool va[9] = { vh0 && vw0, vh0, vh0 && vw2,
                   vw0,        true, vw2,
                   vh2 && vw0, vh2, vh2 && vw2 };
    const int offA[9] = { -65, -64, -63, -1, 0, 1, 63, 64, 65 };
    float ax = 0.f, ay = 0.f, az = 0.f, aw = 0.f;
    int f = 0;
    for (int c = 0; c < CINN; ++c) {
        const float* xp = xb + (c << 12);
        #pragma unroll
        for (int a = 0; a < 9; ++a) {
            float val = va[a] ? xp[offA[a]] : 0.f;
            float q = val * wp[f];
            float4 bb = *reinterpret_cast<const float4*>(&bl[(f << 5) + co4]);
            ax += q * bb.x; ay += q * bb.y; az += q * bb.z; aw += q * bb.w;
            ++f;
        }
    }
    const float* wo = wcoutA + ((size_t)b * KCL + k) * COUTT + co4;
    const float* bo = biasA + ((size_t)b * KCL + k) * COUTT + co4;
    float* op = out + ((size_t)(b * COUTT + co4) << 12) + s;
    op[0]     = wo[0] * ax + bo[0];
    op[4096]  = wo[1] * ay + bo[1];
    op[8192]  = wo[2] * az + bo[2];
    op[12288] = wo[3] * aw + bo[3];
}

extern "C" void kernel_launch(void* const* d_in, const int* in_sizes, int n_in,
                              void* d_out, int out_size, void* d_ws, size_t ws_size,
                              hipStream_t stream) {
    (void)in_sizes; (void)n_in; (void)out_size; (void)ws_size;
    const float* x      = (const float*)d_in[0];
    const float* kh_w1  = (const float*)d_in[1];
    const float* kh_b1  = (const float*)d_in[2];
    const float* kh_w2  = (const float*)d_in[3];
    const float* kh_b2  = (const float*)d_in[4];
    const float* area_w = (const float*)d_in[5];
    const float* area_b = (const float*)d_in[6];
    const float* cin_w  = (const float*)d_in[7];
    const float* cin_b  = (const float*)d_in[8];
    const float* cout_w = (const float*)d_in[9];
    const float* cout_b = (const float*)d_in[10];
    const float* base   = (const float*)d_in[11];
    const float* bh_w1  = (const float*)d_in[12];
    const float* bh_b1  = (const float*)d_in[13];
    const float* bh_w2  = (const float*)d_in[14];
    const float* bh_b2  = (const float*)d_in[15];
    const float* bh_w3  = (const float*)d_in[16];
    const float* bh_b3  = (const float*)d_in[17];
    float* out = (float*)d_out;

    unsigned* barcnt = (unsigned*)d_ws;                    // BB lines of 64B
    unsigned* barver = barcnt + 16 * BB;                   // BB lines of 64B
    float* centG = (float*)(barver + 16 * BB);             // BB*1024
    float* psums = centG + BB * 1024;                      // 2*NB*1024 = 131072
    float* pcnts = psums + (size_t)2 * NB * 1024;          // 2*NB*32   = 4096
    int*   idx   = (int*)(pcnts + 2 * NB * KCL);           // B*S
    float* wprod = (float*)(idx + BB * SS);                // B*K*F
    float* wco   = wprod + (size_t)BB * KCL * FF;          // B*K*COUT
    float* bia   = wco + BB * KCL * COUTT;                 // B*K*COUT

    (void)hipMemsetAsync(barcnt, 0, 2 * 16 * BB * sizeof(unsigned), stream);
    kmeans_mlp_fused<<<NB, TPB, 0, stream>>>(x, idx, psums, pcnts, barcnt, barver, centG,
                                             kh_w1, kh_b1, kh_w2, kh_b2,
                                             area_w, area_b, cin_w, cin_b, cout_w, cout_b,
                                             bh_w1, bh_b1, bh_w2, bh_b2, bh_w3, bh_b3,
                                             wprod, wco, bia);
    conv_kernel<<<BB * 128, 256, 0, stream>>>(x, idx, wprod, wco, bia, base, out);
}